// Round 18
// baseline (550.813 us; speedup 1.0000x reference)
//
#include <hip/hip_runtime.h>
#include <hip/hip_bf16.h>

#define HDIM 64
#define LSEQ 1024
#define NB 64
#define NV 32000
#define CC 32            // chunk length
#define NCH 32           // chunks per sequence
#define NT (NB * LSEQ)   // total tokens = kallT row stride

// ---------- DPP cross-lane sums (pure VALU) ----------
template<int CTRL>
__device__ __forceinline__ float dpp_red(float x) {
  int y = __builtin_amdgcn_update_dpp(0, __float_as_int(x), CTRL, 0xF, 0xF, true);
  return x + __int_as_float(y);
}
__device__ __forceinline__ float quad_sum(float x) {
  x = dpp_red<0xB1>(x);    // xor 1
  x = dpp_red<0x4E>(x);    // xor 2
  return x;
}
// full-wave sum ending in lane 63 (6 dependent DPP adds, no SALU mixing)
__device__ __forceinline__ float wave_sum63(float x) {
  x = dpp_red<0xB1>(x);    // xor 1
  x = dpp_red<0x4E>(x);    // xor 2
  x = dpp_red<0x141>(x);   // row_half_mirror -> sum of 8
  x = dpp_red<0x140>(x);   // row_mirror      -> sum of 16 (row sums)
  x = dpp_red<0x142>(x);   // + row_bcast15   -> lane63 accumulates rows
  x = dpp_red<0x143>(x);   // + row_bcast31   -> lane 63 holds full sum
  return x;
}

// ---------- Kernel 0: transpose W1 (64x128 -> 128x64) and kpW (64x64) ----------
__global__ __launch_bounds__(256) void transpose_w(const float* __restrict__ W1,
    const float* __restrict__ kpW, float* __restrict__ W1T, float* __restrict__ kpWT)
{
  const int tid = blockIdx.x * 256 + threadIdx.x;
  if (tid < 8192) { const int c = tid >> 6, j = tid & 63; W1T[tid] = W1[j * 128 + c]; }
  else { const int e = tid - 8192; const int i = e >> 6, j = e & 63; kpWT[e] = kpW[j * 64 + i]; }
}

// ---------- Kernel 1: token transform, lane = token ----------
__global__ __launch_bounds__(256, 1) void tok4(
    const int* __restrict__ seq, const float* __restrict__ embed,
    const float* __restrict__ W1T, const float* __restrict__ b1,
    const float* __restrict__ W2, const float* __restrict__ b2,
    const float* __restrict__ gamma, const float* __restrict__ beta,
    const float* __restrict__ kpWT, float* __restrict__ kallT,
    float* __restrict__ thr2_all, float* __restrict__ inv_all)
{
  const int tok = blockIdx.x * 256 + threadIdx.x;
  const int row = seq[tok];
  float h[64], x[64];
  const float4* ep = (const float4*)(embed + (size_t)row * HDIM);
  #pragma unroll
  for (int q = 0; q < 16; ++q) {
    const float4 v = ep[q];
    h[4*q] = v.x; h[4*q+1] = v.y; h[4*q+2] = v.z; h[4*q+3] = v.w;
  }
  #pragma unroll
  for (int j = 0; j < 64; ++j) x[j] = h[j] + b2[j];

  for (int c = 0; c < 128; ++c) {
    const float* w1r = W1T + c * 64;                   // uniform row -> s_load
    float a0 = 0.f, a1 = 0.f, a2 = 0.f, a3 = 0.f;
    #pragma unroll
    for (int j = 0; j < 64; j += 4) {
      a0 = fmaf(h[j],   w1r[j],   a0);
      a1 = fmaf(h[j+1], w1r[j+1], a1);
      a2 = fmaf(h[j+2], w1r[j+2], a2);
      a3 = fmaf(h[j+3], w1r[j+3], a3);
    }
    const float y = fmaxf(b1[c] + ((a0 + a1) + (a2 + a3)), 0.f);
    const float* w2r = W2 + c * 64;
    #pragma unroll
    for (int j = 0; j < 64; ++j) x[j] = fmaf(y, w2r[j], x[j]);
  }

  float s0=0.f,s1=0.f,s2=0.f,s3=0.f,q0=0.f,q1=0.f,q2=0.f,q3=0.f;
  #pragma unroll
  for (int j = 0; j < 64; j += 4) {
    s0 += x[j]; s1 += x[j+1]; s2 += x[j+2]; s3 += x[j+3];
    q0 = fmaf(x[j],   x[j],   q0); q1 = fmaf(x[j+1], x[j+1], q1);
    q2 = fmaf(x[j+2], x[j+2], q2); q3 = fmaf(x[j+3], x[j+3], q3);
  }
  const float mu  = ((s0+s1)+(s2+s3)) * (1.f/64.f);
  const float var = ((q0+q1)+(q2+q3)) * (1.f/64.f) - mu * mu;
  const float rs  = rsqrtf(var + 1e-5f);
  #pragma unroll
  for (int j = 0; j < 64; ++j) h[j] = (x[j] - mu) * rs * gamma[j] + beta[j];

  float nk2 = 0.f;
  for (int i = 0; i < 64; ++i) {
    const float* kr = kpWT + i * 64;                   // uniform row -> s_load
    float c0=0.f,c1=0.f,c2=0.f,c3=0.f;
    #pragma unroll
    for (int j = 0; j < 64; j += 4) {
      c0 = fmaf(h[j],   kr[j],   c0);
      c1 = fmaf(h[j+1], kr[j+1], c1);
      c2 = fmaf(h[j+2], kr[j+2], c2);
      c3 = fmaf(h[j+3], kr[j+3], c3);
    }
    const float ki = (c0 + c1) + (c2 + c3);
    nk2 = fmaf(ki, ki, nk2);
    kallT[(size_t)i * NT + tok] = ki;
  }
  thr2_all[tok] = 0.16f * nk2;
  inv_all[tok]  = 1.f / fmaxf(sqrtf(nk2), 1e-12f);
}

// ---------- Kernel 2: per-chunk normalized Gram ----------
__global__ __launch_bounds__(64) void gram2(const float* __restrict__ kallT,
    const float* __restrict__ inv_all, float* __restrict__ Gg)
{
  const int bi = blockIdx.x;
  const int b = bi >> 5, ch = bi & 31;
  const int l = threadIdx.x;
  const int t0 = (l & 7) * 4, s0 = (l >> 3) * 4;
  const size_t gb = (size_t)b * LSEQ + ch * CC;
  float g00=0,g01=0,g02=0,g03=0, g10=0,g11=0,g12=0,g13=0;
  float g20=0,g21=0,g22=0,g23=0, g30=0,g31=0,g32=0,g33=0;
  for (int j = 0; j < 64; ++j) {
    const float* rowp = kallT + (size_t)j * NT + gb;
    const float4 a = *(const float4*)(rowp + t0);
    const float4 c = *(const float4*)(rowp + s0);
    g00=fmaf(a.x,c.x,g00); g01=fmaf(a.x,c.y,g01); g02=fmaf(a.x,c.z,g02); g03=fmaf(a.x,c.w,g03);
    g10=fmaf(a.y,c.x,g10); g11=fmaf(a.y,c.y,g11); g12=fmaf(a.y,c.z,g12); g13=fmaf(a.y,c.w,g13);
    g20=fmaf(a.z,c.x,g20); g21=fmaf(a.z,c.y,g21); g22=fmaf(a.z,c.z,g22); g23=fmaf(a.z,c.w,g23);
    g30=fmaf(a.w,c.x,g30); g31=fmaf(a.w,c.y,g31); g32=fmaf(a.w,c.z,g32); g33=fmaf(a.w,c.w,g33);
  }
  const float4 it = *(const float4*)(inv_all + gb + t0);
  const float4 is = *(const float4*)(inv_all + gb + s0);
  float* Go = Gg + (size_t)bi * (CC * CC);
  float4 o;
  o.x=g00*it.x*is.x; o.y=g01*it.x*is.y; o.z=g02*it.x*is.z; o.w=g03*it.x*is.w;
  *(float4*)(Go + (t0+0)*CC + s0) = o;
  o.x=g10*it.y*is.x; o.y=g11*it.y*is.y; o.z=g12*it.y*is.z; o.w=g13*it.y*is.w;
  *(float4*)(Go + (t0+1)*CC + s0) = o;
  o.x=g20*it.z*is.x; o.y=g21*it.z*is.y; o.z=g22*it.z*is.z; o.w=g23*it.z*is.w;
  *(float4*)(Go + (t0+2)*CC + s0) = o;
  o.x=g30*it.w*is.x; o.y=g31*it.w*is.y; o.z=g32*it.w*is.z; o.w=g33*it.w*is.w;
  *(float4*)(Go + (t0+3)*CC + s0) = o;
}

// ---------- Kernel 3: chunked gated delta scan, 3 waves, 3 phases/chunk ----------
// Round-7 measured-best structure (192 thr; helpers w1,w2 hold M as 2 rows x 16
// cols/lane with register double-buffered prefetch), with ONE change: all of
// wave-0's uniform-address data (G rows, thr2) is read directly from GLOBAL
// (scalar/L2 path) instead of LDS -> removes ~270 LDS instructions per chunk
// (GS staging writes, 8x ds_read_b128 G per token, thr2S) from the saturated
// LDS pipe. kS/rS/cstS/invS stay in LDS (cross-wave or per-lane data).
__global__ __launch_bounds__(192, 1) void scan6(
    const float* __restrict__ kallT, const float* __restrict__ thr2_all,
    const float* __restrict__ inv_all, const float* __restrict__ Gg,
    float* __restrict__ readv)
{
  __shared__ float kS[3][CC * 68];
  __shared__ float rS[CC * 64];
  __shared__ float cstS[CC * 64];
  __shared__ float invS[3][CC];

  const int b = blockIdx.x, tid = threadIdx.x;
  const int w = tid >> 6, l = tid & 63;
  const int A = l >> 2, B4 = l & 3;
  const int r0 = 32 * (w - 1) + 2 * A;   // helper rows (w>0)
  const int jb = 16 * B4;
  const size_t gbase = (size_t)b * LSEQ;

  float M0[16], M1[16], acc[32];
  #pragma unroll
  for (int q = 0; q < 16; ++q) { M0[q] = 0.f; M1[q] = 0.f; }

// A2 over 16 tokens with k/inv double-buffered register prefetch.
#define A2_RUN16(KB, IB, T0) do {                                              \
    const float* kr0_ = &kS[KB][(T0) * 68 + jb];                               \
    float4 kA0 = ((const float4*)kr0_)[0], kA1 = ((const float4*)kr0_)[1],     \
           kA2 = ((const float4*)kr0_)[2], kA3 = ((const float4*)kr0_)[3];     \
    float  ivA = invS[IB][(T0)];                                               \
    float4 kB0, kB1, kB2, kB3; float ivB = 0.f;                                \
    _Pragma("unroll")                                                          \
    for (int i = 0; i < 16; ++i) {                                             \
      const int t = (T0) + i;                                                  \
      if (i < 15) {                                                            \
        const float* knx_ = &kS[KB][(t + 1) * 68 + jb];                        \
        if ((i & 1) == 0) {                                                    \
          kB0 = ((const float4*)knx_)[0]; kB1 = ((const float4*)knx_)[1];      \
          kB2 = ((const float4*)knx_)[2]; kB3 = ((const float4*)knx_)[3];      \
          ivB = invS[IB][t + 1];                                               \
        } else {                                                               \
          kA0 = ((const float4*)knx_)[0]; kA1 = ((const float4*)knx_)[1];      \
          kA2 = ((const float4*)knx_)[2]; kA3 = ((const float4*)knx_)[3];      \
          ivA = invS[IB][t + 1];                                               \
        }                                                                      \
      }                                                                        \
      float4 kq[4]; float iv;                                                  \
      if ((i & 1) == 0) { kq[0]=kA0; kq[1]=kA1; kq[2]=kA2; kq[3]=kA3; iv=ivA; }\
      else              { kq[0]=kB0; kq[1]=kB1; kq[2]=kB2; kq[3]=kB3; iv=ivB; }\
      float p0a=0.f,p0b=0.f,p1a=0.f,p1b=0.f;                                   \
      _Pragma("unroll")                                                        \
      for (int q2 = 0; q2 < 4; ++q2) {                                         \
        const float4 kv = kq[q2];                                              \
        p0a = fmaf(M0[4*q2+0], kv.x, p0a); p0b = fmaf(M0[4*q2+1], kv.y, p0b);  \
        p0a = fmaf(M0[4*q2+2], kv.z, p0a); p0b = fmaf(M0[4*q2+3], kv.w, p0b);  \
        p1a = fmaf(M1[4*q2+0], kv.x, p1a); p1b = fmaf(M1[4*q2+1], kv.y, p1b);  \
        p1a = fmaf(M1[4*q2+2], kv.z, p1a); p1b = fmaf(M1[4*q2+3], kv.w, p1b);  \
      }                                                                        \
      float p0 = quad_sum(p0a + p0b);                                          \
      float p1 = quad_sum(p1a + p1b);                                          \
      if (B4 == 0) *(float2*)&rS[t * 64 + r0] = make_float2(p0 * iv, p1 * iv); \
    }                                                                          \
  } while (0)

// C over 16 tokens with k/cst/inv double-buffered register prefetch.
#define C_RUN16(KB, IB, S0) do {                                               \
    const float* kr0_ = &kS[KB][(S0) * 68 + jb];                               \
    float4 kA0 = ((const float4*)kr0_)[0], kA1 = ((const float4*)kr0_)[1],     \
           kA2 = ((const float4*)kr0_)[2], kA3 = ((const float4*)kr0_)[3];     \
    float2 cA  = *(const float2*)&cstS[(S0) * 64 + r0];                        \
    float  ivA = invS[IB][(S0)];                                               \
    float4 kB0, kB1, kB2, kB3; float2 cB = make_float2(0.f, 0.f); float ivB = 0.f; \
    _Pragma("unroll")                                                          \
    for (int i = 0; i < 16; ++i) {                                             \
      const int s = (S0) + i;                                                  \
      if (i < 15) {                                                            \
        const float* knx_ = &kS[KB][(s + 1) * 68 + jb];                        \
        if ((i & 1) == 0) {                                                    \
          kB0 = ((const float4*)knx_)[0]; kB1 = ((const float4*)knx_)[1];      \
          kB2 = ((const float4*)knx_)[2]; kB3 = ((const float4*)knx_)[3];      \
          cB  = *(const float2*)&cstS[(s + 1) * 64 + r0];                      \
          ivB = invS[IB][s + 1];                                               \
        } else {                                                               \
          kA0 = ((const float4*)knx_)[0]; kA1 = ((const float4*)knx_)[1];      \
          kA2 = ((const float4*)knx_)[2]; kA3 = ((const float4*)knx_)[3];      \
          cA  = *(const float2*)&cstS[(s + 1) * 64 + r0];                      \
          ivA = invS[IB][s + 1];                                               \
        }                                                                      \
      }                                                                        \
      float4 kq[4]; float2 cc2; float iv;                                      \
      if ((i & 1) == 0) { kq[0]=kA0; kq[1]=kA1; kq[2]=kA2; kq[3]=kA3; cc2=cA; iv=ivA; } \
      else              { kq[0]=kB0; kq[1]=kB1; kq[2]=kB2; kq[3]=kB3; cc2=cB; iv=ivB; } \
      const float c0 = cc2.x * iv, c1 = cc2.y * iv;                            \
      _Pragma("unroll")                                                        \
      for (int q2 = 0; q2 < 4; ++q2) {                                         \
        const float4 kv = kq[q2];                                              \
        M0[4*q2+0] = fmaf(c0, kv.x, M0[4*q2+0]); M0[4*q2+1] = fmaf(c0, kv.y, M0[4*q2+1]); \
        M0[4*q2+2] = fmaf(c0, kv.z, M0[4*q2+2]); M0[4*q2+3] = fmaf(c0, kv.w, M0[4*q2+3]); \
        M1[4*q2+0] = fmaf(c1, kv.x, M1[4*q2+0]); M1[4*q2+1] = fmaf(c1, kv.y, M1[4*q2+1]); \
        M1[4*q2+2] = fmaf(c1, kv.z, M1[4*q2+2]); M1[4*q2+3] = fmaf(c1, kv.w, M1[4*q2+3]); \
      }                                                                        \
    }                                                                          \
  } while (0)

// B: serial gate core, tokens [8Q, 8Q+8). G rows + thr2 come from GLOBAL via
// uniform addresses (gch/thg, scalar/L2 path) -> zero LDS traffic for them.
// G prefetch: token t's row in g2_[i&1]; t+1's row loaded into g2_[(i+1)&1].
#define B_SLICE(Q, CBUF, LASTCH) do {                                          \
    const int t0_ = 8 * (Q);                                                   \
    const float* thp_ = thg + t0_;                                             \
    float th8[8];                                                              \
    _Pragma("unroll")                                                          \
    for (int i = 0; i < 8; ++i) th8[i] = thp_[i];                              \
    float kr_[8], rr_[8];                                                      \
    _Pragma("unroll")                                                          \
    for (int i = 0; i < 8; ++i) {                                              \
      kr_[i] = kS[CBUF][(t0_ + i) * 68 + l];                                   \
      rr_[i] = rS[(t0_ + i) * 64 + l];                                         \
    }                                                                          \
    float g2_[2][32];                                                          \
    _Pragma("unroll")                                                          \
    for (int q = (t0_ + 1) >> 2; q < 8; ++q) {                                 \
      const float4 v = ((const float4*)(gch + t0_ * 32))[q];                   \
      g2_[0][4*q+0] = v.x; g2_[0][4*q+1] = v.y;                                \
      g2_[0][4*q+2] = v.z; g2_[0][4*q+3] = v.w;                                \
    }                                                                          \
    float err_ = acc[t0_] + kr_[0] - rr_[0];                                   \
    float red_ = wave_sum63(err_ * err_);                                      \
    _Pragma("unroll")                                                          \
    for (int i = 0; i < 8; ++i) {                                              \
      const int t = t0_ + i;                                                   \
      if (i < 7) {                                                             \
        _Pragma("unroll")                                                      \
        for (int q = (t + 2) >> 2; q < 8; ++q) {                               \
          const float4 v = ((const float4*)(gch + (t + 1) * 32))[q];           \
          g2_[(i+1)&1][4*q+0] = v.x; g2_[(i+1)&1][4*q+1] = v.y;                \
          g2_[(i+1)&1][4*q+2] = v.z; g2_[(i+1)&1][4*q+3] = v.w;                \
        }                                                                      \
      }                                                                        \
      const float ne2_ = __int_as_float(                                       \
          __builtin_amdgcn_readlane(__float_as_int(red_), 63));                \
      bool gate_ = (ne2_ >= th8[i]);                                           \
      if ((LASTCH) && t == CC - 1) gate_ = false;                              \
      const float c = gate_ ? err_ : 0.f;                                      \
      cstS[t * 64 + l] = c;                                                    \
      if (i < 7) {                                                             \
        acc[t + 1] = fmaf(-g2_[i & 1][t + 1], c, acc[t + 1]);                  \
        err_ = acc[t + 1] + kr_[i + 1] - rr_[i + 1];                           \
        red_ = wave_sum63(err_ * err_);                                        \
      }                                                                        \
      _Pragma("unroll")                                                        \
      for (int u = (i < 7) ? (t + 2) : (t + 1); u < CC; ++u)                   \
        acc[u] = fmaf(-g2_[i & 1][u], c, acc[u]);                              \
    }                                                                          \
  } while (0)

  // ---- prologue: stage chunk 0 (k rows + inv only; no G/thr2 in LDS) ----
  if (w < 2) {
    const float* src = kallT + (size_t)l * NT + gbase + w * 16;
    float4 v[4];
    #pragma unroll
    for (int q = 0; q < 4; ++q) v[q] = ((const float4*)src)[q];
    #pragma unroll
    for (int q = 0; q < 4; ++q) {
      const int t0 = w * 16 + q * 4;
      kS[0][(t0+0)*68 + l] = v[q].x; kS[0][(t0+1)*68 + l] = v[q].y;
      kS[0][(t0+2)*68 + l] = v[q].z; kS[0][(t0+3)*68 + l] = v[q].w;
    }
  } else {
    if (l < CC) invS[0][l] = inv_all[gbase + l];
  }
  __syncthreads();

  for (int ch = 0; ch < NCH; ++ch) {
    const int cb = ch % 3, pb = (ch + 2) % 3, nb = (ch + 1) % 3;
    const bool lastch = (ch == NCH - 1);
    const float* gch = Gg + ((size_t)b * NCH + ch) * (CC * CC);   // uniform
    const float* thg = thr2_all + gbase + (size_t)ch * CC;        // uniform

    // ---- P0: w0: reset acc + stage k/inv of ch+1 ; helpers: C(ch-1)[16..32) + A2(ch)[0..16) ----
    if (w == 0) {
      #pragma unroll
      for (int u = 0; u < 32; ++u) acc[u] = 0.f;
      if (!lastch) {
        const float* src = kallT + (size_t)l * NT + gbase + (ch + 1) * CC;
        float4 v[8];
        #pragma unroll
        for (int q = 0; q < 8; ++q) v[q] = ((const float4*)src)[q];
        #pragma unroll
        for (int q = 0; q < 8; ++q) {
          const int t0 = q * 4;
          kS[nb][(t0+0)*68 + l] = v[q].x; kS[nb][(t0+1)*68 + l] = v[q].y;
          kS[nb][(t0+2)*68 + l] = v[q].z; kS[nb][(t0+3)*68 + l] = v[q].w;
        }
        if (l < CC) invS[nb][l] = inv_all[gbase + (ch + 1) * CC + l];
      }
    } else {
      if (ch > 0) C_RUN16(pb, pb, 16);
      A2_RUN16(cb, cb, 0);
    }
    __syncthreads();

    // ---- P1: w0: B[0..16) ; helpers: A2[16..32) ----
    if (w == 0) { B_SLICE(0, cb, lastch); B_SLICE(1, cb, lastch); }
    else        A2_RUN16(cb, cb, 16);
    __syncthreads();

    // ---- P2: w0: B[16..32) ; helpers: C(ch)[0..16) ----
    if (w == 0) { B_SLICE(2, cb, lastch); B_SLICE(3, cb, lastch); }
    else        C_RUN16(cb, cb, 0);
    __syncthreads();
  }

  // ---- epilogue: C(31)[16..32) tail + final read (helpers) ----
  {
    constexpr int fb = (NCH - 1) % 3;   // = 1
    if (w > 0) {
      C_RUN16(fb, fb, 16);
      const float* kr = &kS[fb][(CC - 1) * 68 + jb];
      float p0a=0.f,p0b=0.f,p1a=0.f,p1b=0.f;
      #pragma unroll
      for (int q2 = 0; q2 < 4; ++q2) {
        const float4 kv = ((const float4*)kr)[q2];
        p0a = fmaf(M0[4*q2+0], kv.x, p0a); p0b = fmaf(M0[4*q2+1], kv.y, p0b);
        p0a = fmaf(M0[4*q2+2], kv.z, p0a); p0b = fmaf(M0[4*q2+3], kv.w, p0b);
        p1a = fmaf(M1[4*q2+0], kv.x, p1a); p1b = fmaf(M1[4*q2+1], kv.y, p1b);
        p1a = fmaf(M1[4*q2+2], kv.z, p1a); p1b = fmaf(M1[4*q2+3], kv.w, p1b);
      }
      float d0 = quad_sum(p0a + p0b);
      float d1 = quad_sum(p1a + p1b);
      if (B4 == 0) *(float2*)&readv[b * 64 + r0] = make_float2(d0, d1);
    }
  }
#undef A2_RUN16
#undef C_RUN16
#undef B_SLICE
}

// ---------- Kernel 4: r2T[i][b] = (read @ rpW + rpb)^T ----------
__global__ __launch_bounds__(64) void rproj_kernel(const float* __restrict__ readv,
    const float* __restrict__ rpW, const float* __restrict__ rpb, float* __restrict__ r2T)
{
  const int b = blockIdx.x, i = threadIdx.x;
  const float* rv = readv + b * 64;
  float acc = rpb[i];
  #pragma unroll
  for (int j = 0; j < 64; ++j)
    acc = fmaf(rv[j], rpW[j * 64 + i], acc);
  r2T[i * 64 + b] = acc;
}

// ---------- Kernel 5: out = r2 @ outW + outb (128-thread blocks -> all CUs) ----------
__global__ __launch_bounds__(128, 1) void out_kernel(const float* __restrict__ r2T,
    const float* __restrict__ outW, const float* __restrict__ outb,
    float* __restrict__ out)
{
  const int v = blockIdx.x * 128 + threadIdx.x;
  float acc[64];
  #pragma unroll
  for (int b = 0; b < 64; ++b) acc[b] = 0.f;
  for (int k = 0; k < 64; ++k) {
    const float wv = outW[(size_t)k * NV + v];
    const float* rr = r2T + k * 64;           // uniform row -> s_load
    #pragma unroll
    for (int b = 0; b < 64; ++b)
      acc[b] = fmaf(rr[b], wv, acc[b]);
  }
  const float ob = outb[v];
  #pragma unroll
  for (int b = 0; b < 64; ++b)
    out[(size_t)b * NV + v] = acc[b] + ob;
}

extern "C" void kernel_launch(void* const* d_in, const int* in_sizes, int n_in,
                              void* d_out, int out_size, void* d_ws, size_t ws_size,
                              hipStream_t stream)
{
  const int*   seq   = (const int*)d_in[0];
  const float* embed = (const float*)d_in[1];
  const float* W1    = (const float*)d_in[2];
  const float* b1    = (const float*)d_in[3];
  const float* W2    = (const float*)d_in[4];
  const float* b2    = (const float*)d_in[5];
  const float* gam   = (const float*)d_in[6];
  const float* bet   = (const float*)d_in[7];
  const float* kpW   = (const float*)d_in[8];
  const float* rpW   = (const float*)d_in[9];
  const float* rpb   = (const float*)d_in[10];
  const float* outW  = (const float*)d_in[11];
  const float* outb  = (const float*)d_in[12];
  float* out = (float*)d_out;

  float* ws = (float*)d_ws;
  float* kallT = ws;                                    // 4,194,304 f  [feat][tok]
  float* G     = kallT + (size_t)HDIM * NT;             // 2,097,152 f
  float* thr2  = G     + (size_t)NB * NCH * CC * CC;    //    65,536 f
  float* inv   = thr2  + NT;                            //    65,536 f
  float* readv = inv   + NT;                            //     4,096 f
  float* r2T   = readv + NB * HDIM;                     //     4,096 f
  float* W1T   = r2T   + NB * HDIM;                     //     8,192 f
  float* kpWT  = W1T   + 8192;                          //     4,096 f

  hipLaunchKernelGGL(transpose_w, dim3(48), dim3(256), 0, stream, W1, kpW, W1T, kpWT);
  hipLaunchKernelGGL(tok4, dim3(256), dim3(256), 0, stream,
                     seq, embed, W1T, b1, W2, b2, gam, bet, kpWT, kallT, thr2, inv);
  hipLaunchKernelGGL(gram2, dim3(NB * NCH), dim3(64), 0, stream, kallT, inv, G);
  hipLaunchKernelGGL(scan6, dim3(NB), dim3(192), 0, stream, kallT, thr2, inv, G, readv);
  hipLaunchKernelGGL(rproj_kernel, dim3(NB), dim3(64), 0, stream, readv, rpW, rpb, r2T);
  hipLaunchKernelGGL(out_kernel, dim3(NV / 128), dim3(128), 0, stream, r2T, outW, outb, out);
}

// Round 21
// 462.298 us; speedup vs baseline: 1.1915x; 1.1915x over previous
//
#include <hip/hip_runtime.h>
#include <hip/hip_bf16.h>

#define HDIM 64
#define LSEQ 1024
#define NB 64
#define NV 32000
#define CC 32            // chunk length
#define NCH 32           // chunks per sequence
#define NT (NB * LSEQ)   // total tokens = kallT row stride

// ---------- DPP cross-lane sums (pure VALU) ----------
template<int CTRL>
__device__ __forceinline__ float dpp_red(float x) {
  int y = __builtin_amdgcn_update_dpp(0, __float_as_int(x), CTRL, 0xF, 0xF, true);
  return x + __int_as_float(y);
}
__device__ __forceinline__ float quad_sum(float x) {
  x = dpp_red<0xB1>(x);    // xor 1
  x = dpp_red<0x4E>(x);    // xor 2
  return x;
}
// full-wave sum ending in lane 63 (6 dependent DPP adds, no SALU mixing)
__device__ __forceinline__ float wave_sum63(float x) {
  x = dpp_red<0xB1>(x);    // xor 1
  x = dpp_red<0x4E>(x);    // xor 2
  x = dpp_red<0x141>(x);   // row_half_mirror -> sum of 8
  x = dpp_red<0x140>(x);   // row_mirror      -> sum of 16 (row sums)
  x = dpp_red<0x142>(x);   // + row_bcast15   -> lane63 accumulates rows
  x = dpp_red<0x143>(x);   // + row_bcast31   -> lane 63 holds full sum
  return x;
}

// ---------- Kernel 0: transpose W1 (64x128 -> 128x64) and kpW (64x64) ----------
__global__ __launch_bounds__(256) void transpose_w(const float* __restrict__ W1,
    const float* __restrict__ kpW, float* __restrict__ W1T, float* __restrict__ kpWT)
{
  const int tid = blockIdx.x * 256 + threadIdx.x;
  if (tid < 8192) { const int c = tid >> 6, j = tid & 63; W1T[tid] = W1[j * 128 + c]; }
  else { const int e = tid - 8192; const int i = e >> 6, j = e & 63; kpWT[e] = kpW[j * 64 + i]; }
}

// ---------- Kernel 1: token transform, lane = token ----------
__global__ __launch_bounds__(256, 1) void tok4(
    const int* __restrict__ seq, const float* __restrict__ embed,
    const float* __restrict__ W1T, const float* __restrict__ b1,
    const float* __restrict__ W2, const float* __restrict__ b2,
    const float* __restrict__ gamma, const float* __restrict__ beta,
    const float* __restrict__ kpWT, float* __restrict__ kallT,
    float* __restrict__ thr2_all, float* __restrict__ inv_all)
{
  const int tok = blockIdx.x * 256 + threadIdx.x;
  const int row = seq[tok];
  float h[64], x[64];
  const float4* ep = (const float4*)(embed + (size_t)row * HDIM);
  #pragma unroll
  for (int q = 0; q < 16; ++q) {
    const float4 v = ep[q];
    h[4*q] = v.x; h[4*q+1] = v.y; h[4*q+2] = v.z; h[4*q+3] = v.w;
  }
  #pragma unroll
  for (int j = 0; j < 64; ++j) x[j] = h[j] + b2[j];

  for (int c = 0; c < 128; ++c) {
    const float* w1r = W1T + c * 64;                   // uniform row -> s_load
    float a0 = 0.f, a1 = 0.f, a2 = 0.f, a3 = 0.f;
    #pragma unroll
    for (int j = 0; j < 64; j += 4) {
      a0 = fmaf(h[j],   w1r[j],   a0);
      a1 = fmaf(h[j+1], w1r[j+1], a1);
      a2 = fmaf(h[j+2], w1r[j+2], a2);
      a3 = fmaf(h[j+3], w1r[j+3], a3);
    }
    const float y = fmaxf(b1[c] + ((a0 + a1) + (a2 + a3)), 0.f);
    const float* w2r = W2 + c * 64;
    #pragma unroll
    for (int j = 0; j < 64; ++j) x[j] = fmaf(y, w2r[j], x[j]);
  }

  float s0=0.f,s1=0.f,s2=0.f,s3=0.f,q0=0.f,q1=0.f,q2=0.f,q3=0.f;
  #pragma unroll
  for (int j = 0; j < 64; j += 4) {
    s0 += x[j]; s1 += x[j+1]; s2 += x[j+2]; s3 += x[j+3];
    q0 = fmaf(x[j],   x[j],   q0); q1 = fmaf(x[j+1], x[j+1], q1);
    q2 = fmaf(x[j+2], x[j+2], q2); q3 = fmaf(x[j+3], x[j+3], q3);
  }
  const float mu  = ((s0+s1)+(s2+s3)) * (1.f/64.f);
  const float var = ((q0+q1)+(q2+q3)) * (1.f/64.f) - mu * mu;
  const float rs  = rsqrtf(var + 1e-5f);
  #pragma unroll
  for (int j = 0; j < 64; ++j) h[j] = (x[j] - mu) * rs * gamma[j] + beta[j];

  float nk2 = 0.f;
  for (int i = 0; i < 64; ++i) {
    const float* kr = kpWT + i * 64;                   // uniform row -> s_load
    float c0=0.f,c1=0.f,c2=0.f,c3=0.f;
    #pragma unroll
    for (int j = 0; j < 64; j += 4) {
      c0 = fmaf(h[j],   kr[j],   c0);
      c1 = fmaf(h[j+1], kr[j+1], c1);
      c2 = fmaf(h[j+2], kr[j+2], c2);
      c3 = fmaf(h[j+3], kr[j+3], c3);
    }
    const float ki = (c0 + c1) + (c2 + c3);
    nk2 = fmaf(ki, ki, nk2);
    kallT[(size_t)i * NT + tok] = ki;
  }
  thr2_all[tok] = 0.16f * nk2;
  inv_all[tok]  = 1.f / fmaxf(sqrtf(nk2), 1e-12f);
}

// ---------- Kernel 2: per-chunk normalized Gram ----------
__global__ __launch_bounds__(64) void gram2(const float* __restrict__ kallT,
    const float* __restrict__ inv_all, float* __restrict__ Gg)
{
  const int bi = blockIdx.x;
  const int b = bi >> 5, ch = bi & 31;
  const int l = threadIdx.x;
  const int t0 = (l & 7) * 4, s0 = (l >> 3) * 4;
  const size_t gb = (size_t)b * LSEQ + ch * CC;
  float g00=0,g01=0,g02=0,g03=0, g10=0,g11=0,g12=0,g13=0;
  float g20=0,g21=0,g22=0,g23=0, g30=0,g31=0,g32=0,g33=0;
  for (int j = 0; j < 64; ++j) {
    const float* rowp = kallT + (size_t)j * NT + gb;
    const float4 a = *(const float4*)(rowp + t0);
    const float4 c = *(const float4*)(rowp + s0);
    g00=fmaf(a.x,c.x,g00); g01=fmaf(a.x,c.y,g01); g02=fmaf(a.x,c.z,g02); g03=fmaf(a.x,c.w,g03);
    g10=fmaf(a.y,c.x,g10); g11=fmaf(a.y,c.y,g11); g12=fmaf(a.y,c.z,g12); g13=fmaf(a.y,c.w,g13);
    g20=fmaf(a.z,c.x,g20); g21=fmaf(a.z,c.y,g21); g22=fmaf(a.z,c.z,g22); g23=fmaf(a.z,c.w,g23);
    g30=fmaf(a.w,c.x,g30); g31=fmaf(a.w,c.y,g31); g32=fmaf(a.w,c.z,g32); g33=fmaf(a.w,c.w,g33);
  }
  const float4 it = *(const float4*)(inv_all + gb + t0);
  const float4 is = *(const float4*)(inv_all + gb + s0);
  float* Go = Gg + (size_t)bi * (CC * CC);
  float4 o;
  o.x=g00*it.x*is.x; o.y=g01*it.x*is.y; o.z=g02*it.x*is.z; o.w=g03*it.x*is.w;
  *(float4*)(Go + (t0+0)*CC + s0) = o;
  o.x=g10*it.y*is.x; o.y=g11*it.y*is.y; o.z=g12*it.y*is.z; o.w=g13*it.y*is.w;
  *(float4*)(Go + (t0+1)*CC + s0) = o;
  o.x=g20*it.z*is.x; o.y=g21*it.z*is.y; o.z=g22*it.z*is.z; o.w=g23*it.z*is.w;
  *(float4*)(Go + (t0+2)*CC + s0) = o;
  o.x=g30*it.w*is.x; o.y=g31*it.w*is.y; o.z=g32*it.w*is.z; o.w=g33*it.w*is.w;
  *(float4*)(Go + (t0+3)*CC + s0) = o;
}

// ---------- Kernel 3: chunked gated delta scan, 3 waves, 3 phases/chunk ----------
// Measured-best configuration (round 7: scan6 209 us, total 460.6 us).
// wave 0: serial gate core (B) + staging; waves 1-2: helpers (A2 base / C update),
// each owning 32 M rows as 2 rows x 16 cols per lane; helper A2/C use register
// double-buffered prefetch of k/cst/inv so token t+1's LDS loads are in flight
// while token t's FMAs execute.
__global__ __launch_bounds__(192, 1) void scan6(
    const float* __restrict__ kallT, const float* __restrict__ thr2_all,
    const float* __restrict__ inv_all, const float* __restrict__ Gg,
    float* __restrict__ readv)
{
  __shared__ float kS[3][CC * 68];
  __shared__ float GS[2][CC * CC];
  __shared__ float rS[CC * 64];
  __shared__ float cstS[CC * 64];
  __shared__ float thr2S[2][CC];
  __shared__ float invS[3][CC];

  const int b = blockIdx.x, tid = threadIdx.x;
  const int w = tid >> 6, l = tid & 63;
  const int A = l >> 2, B4 = l & 3;
  const int r0 = 32 * (w - 1) + 2 * A;   // helper rows (w>0)
  const int jb = 16 * B4;
  const size_t gbase = (size_t)b * LSEQ;

  float M0[16], M1[16], acc[32];
  #pragma unroll
  for (int q = 0; q < 16; ++q) { M0[q] = 0.f; M1[q] = 0.f; }

// A2 over 16 tokens with k/inv double-buffered register prefetch.
#define A2_RUN16(KB, IB, T0) do {                                              \
    const float* kr0_ = &kS[KB][(T0) * 68 + jb];                               \
    float4 kA0 = ((const float4*)kr0_)[0], kA1 = ((const float4*)kr0_)[1],     \
           kA2 = ((const float4*)kr0_)[2], kA3 = ((const float4*)kr0_)[3];     \
    float  ivA = invS[IB][(T0)];                                               \
    float4 kB0, kB1, kB2, kB3; float ivB = 0.f;                                \
    _Pragma("unroll")                                                          \
    for (int i = 0; i < 16; ++i) {                                             \
      const int t = (T0) + i;                                                  \
      if (i < 15) {                                                            \
        const float* knx_ = &kS[KB][(t + 1) * 68 + jb];                        \
        if ((i & 1) == 0) {                                                    \
          kB0 = ((const float4*)knx_)[0]; kB1 = ((const float4*)knx_)[1];      \
          kB2 = ((const float4*)knx_)[2]; kB3 = ((const float4*)knx_)[3];      \
          ivB = invS[IB][t + 1];                                               \
        } else {                                                               \
          kA0 = ((const float4*)knx_)[0]; kA1 = ((const float4*)knx_)[1];      \
          kA2 = ((const float4*)knx_)[2]; kA3 = ((const float4*)knx_)[3];      \
          ivA = invS[IB][t + 1];                                               \
        }                                                                      \
      }                                                                        \
      float4 kq[4]; float iv;                                                  \
      if ((i & 1) == 0) { kq[0]=kA0; kq[1]=kA1; kq[2]=kA2; kq[3]=kA3; iv=ivA; }\
      else              { kq[0]=kB0; kq[1]=kB1; kq[2]=kB2; kq[3]=kB3; iv=ivB; }\
      float p0a=0.f,p0b=0.f,p1a=0.f,p1b=0.f;                                   \
      _Pragma("unroll")                                                        \
      for (int q2 = 0; q2 < 4; ++q2) {                                         \
        const float4 kv = kq[q2];                                              \
        p0a = fmaf(M0[4*q2+0], kv.x, p0a); p0b = fmaf(M0[4*q2+1], kv.y, p0b);  \
        p0a = fmaf(M0[4*q2+2], kv.z, p0a); p0b = fmaf(M0[4*q2+3], kv.w, p0b);  \
        p1a = fmaf(M1[4*q2+0], kv.x, p1a); p1b = fmaf(M1[4*q2+1], kv.y, p1b);  \
        p1a = fmaf(M1[4*q2+2], kv.z, p1a); p1b = fmaf(M1[4*q2+3], kv.w, p1b);  \
      }                                                                        \
      float p0 = quad_sum(p0a + p0b);                                          \
      float p1 = quad_sum(p1a + p1b);                                          \
      if (B4 == 0) *(float2*)&rS[t * 64 + r0] = make_float2(p0 * iv, p1 * iv); \
    }                                                                          \
  } while (0)

// C over 16 tokens with k/cst/inv double-buffered register prefetch.
#define C_RUN16(KB, IB, S0) do {                                               \
    const float* kr0_ = &kS[KB][(S0) * 68 + jb];                               \
    float4 kA0 = ((const float4*)kr0_)[0], kA1 = ((const float4*)kr0_)[1],     \
           kA2 = ((const float4*)kr0_)[2], kA3 = ((const float4*)kr0_)[3];     \
    float2 cA  = *(const float2*)&cstS[(S0) * 64 + r0];                        \
    float  ivA = invS[IB][(S0)];                                               \
    float4 kB0, kB1, kB2, kB3; float2 cB = make_float2(0.f, 0.f); float ivB = 0.f; \
    _Pragma("unroll")                                                          \
    for (int i = 0; i < 16; ++i) {                                             \
      const int s = (S0) + i;                                                  \
      if (i < 15) {                                                            \
        const float* knx_ = &kS[KB][(s + 1) * 68 + jb];                        \
        if ((i & 1) == 0) {                                                    \
          kB0 = ((const float4*)knx_)[0]; kB1 = ((const float4*)knx_)[1];      \
          kB2 = ((const float4*)knx_)[2]; kB3 = ((const float4*)knx_)[3];      \
          cB  = *(const float2*)&cstS[(s + 1) * 64 + r0];                      \
          ivB = invS[IB][s + 1];                                               \
        } else {                                                               \
          kA0 = ((const float4*)knx_)[0]; kA1 = ((const float4*)knx_)[1];      \
          kA2 = ((const float4*)knx_)[2]; kA3 = ((const float4*)knx_)[3];      \
          cA  = *(const float2*)&cstS[(s + 1) * 64 + r0];                      \
          ivA = invS[IB][s + 1];                                               \
        }                                                                      \
      }                                                                        \
      float4 kq[4]; float2 cc2; float iv;                                      \
      if ((i & 1) == 0) { kq[0]=kA0; kq[1]=kA1; kq[2]=kA2; kq[3]=kA3; cc2=cA; iv=ivA; } \
      else              { kq[0]=kB0; kq[1]=kB1; kq[2]=kB2; kq[3]=kB3; cc2=cB; iv=ivB; } \
      const float c0 = cc2.x * iv, c1 = cc2.y * iv;                            \
      _Pragma("unroll")                                                        \
      for (int q2 = 0; q2 < 4; ++q2) {                                         \
        const float4 kv = kq[q2];                                              \
        M0[4*q2+0] = fmaf(c0, kv.x, M0[4*q2+0]); M0[4*q2+1] = fmaf(c0, kv.y, M0[4*q2+1]); \
        M0[4*q2+2] = fmaf(c0, kv.z, M0[4*q2+2]); M0[4*q2+3] = fmaf(c0, kv.w, M0[4*q2+3]); \
        M1[4*q2+0] = fmaf(c1, kv.x, M1[4*q2+0]); M1[4*q2+1] = fmaf(c1, kv.y, M1[4*q2+1]); \
        M1[4*q2+2] = fmaf(c1, kv.z, M1[4*q2+2]); M1[4*q2+3] = fmaf(c1, kv.w, M1[4*q2+3]); \
      }                                                                        \
    }                                                                          \
  } while (0)

// B: serial gate core, tokens [8Q, 8Q+8), software-pipelined (measured r5-r7)
#define B_SLICE(Q, CBUF, CGI, LASTCH) do {                                     \
    const int t0_ = 8 * (Q);                                                   \
    float kr_[8], rr_[8];                                                      \
    _Pragma("unroll")                                                          \
    for (int i = 0; i < 8; ++i) {                                              \
      kr_[i] = kS[CBUF][(t0_ + i) * 68 + l];                                   \
      rr_[i] = rS[(t0_ + i) * 64 + l];                                         \
    }                                                                          \
    const float4 tha = ((const float4*)&thr2S[CGI][t0_])[0];                   \
    const float4 thb = ((const float4*)&thr2S[CGI][t0_])[1];                   \
    const float th8[8] = {tha.x,tha.y,tha.z,tha.w, thb.x,thb.y,thb.z,thb.w};   \
    float g2_[2][32];                                                          \
    _Pragma("unroll")                                                          \
    for (int q = (t0_ + 1) >> 2; q < 8; ++q) {                                 \
      const float4 v = ((const float4*)&GS[CGI][t0_ * 32])[q];                 \
      g2_[0][4*q+0] = v.x; g2_[0][4*q+1] = v.y;                                \
      g2_[0][4*q+2] = v.z; g2_[0][4*q+3] = v.w;                                \
    }                                                                          \
    float err_ = acc[t0_] + kr_[0] - rr_[0];                                   \
    float red_ = wave_sum63(err_ * err_);                                      \
    _Pragma("unroll")                                                          \
    for (int i = 0; i < 8; ++i) {                                              \
      const int t = t0_ + i;                                                   \
      if (i < 7) {                                                             \
        _Pragma("unroll")                                                      \
        for (int q = (t + 2) >> 2; q < 8; ++q) {                               \
          const float4 v = ((const float4*)&GS[CGI][(t + 1) * 32])[q];         \
          g2_[(i+1)&1][4*q+0] = v.x; g2_[(i+1)&1][4*q+1] = v.y;                \
          g2_[(i+1)&1][4*q+2] = v.z; g2_[(i+1)&1][4*q+3] = v.w;                \
        }                                                                      \
      }                                                                        \
      const float ne2_ = __int_as_float(                                       \
          __builtin_amdgcn_readlane(__float_as_int(red_), 63));                \
      bool gate_ = (ne2_ >= th8[i]);                                           \
      if ((LASTCH) && t == CC - 1) gate_ = false;                              \
      const float c = gate_ ? err_ : 0.f;                                      \
      cstS[t * 64 + l] = c;                                                    \
      if (i < 7) {                                                             \
        acc[t + 1] = fmaf(-g2_[i & 1][t + 1], c, acc[t + 1]);                  \
        err_ = acc[t + 1] + kr_[i + 1] - rr_[i + 1];                           \
        red_ = wave_sum63(err_ * err_);                                        \
      }                                                                        \
      _Pragma("unroll")                                                        \
      for (int u = (i < 7) ? (t + 2) : (t + 1); u < CC; ++u)                   \
        acc[u] = fmaf(-g2_[i & 1][u], c, acc[u]);                              \
    }                                                                          \
  } while (0)

  // ---- prologue: stage chunk 0 ----
  if (w < 2) {
    const float* src = kallT + (size_t)l * NT + gbase + w * 16;
    float4 v[4];
    #pragma unroll
    for (int q = 0; q < 4; ++q) v[q] = ((const float4*)src)[q];
    #pragma unroll
    for (int q = 0; q < 4; ++q) {
      const int t0 = w * 16 + q * 4;
      kS[0][(t0+0)*68 + l] = v[q].x; kS[0][(t0+1)*68 + l] = v[q].y;
      kS[0][(t0+2)*68 + l] = v[q].z; kS[0][(t0+3)*68 + l] = v[q].w;
    }
  } else {
    const float4* gsrc = (const float4*)(Gg + (size_t)b * NCH * (CC * CC));
    float4 g[4];
    #pragma unroll
    for (int q = 0; q < 4; ++q) g[q] = gsrc[q * 64 + l];
    #pragma unroll
    for (int q = 0; q < 4; ++q) ((float4*)GS[0])[q * 64 + l] = g[q];
    if (l < CC) thr2S[0][l] = thr2_all[gbase + l];
    else        invS[0][l - CC] = inv_all[gbase + (l - CC)];
  }
  __syncthreads();

  for (int ch = 0; ch < NCH; ++ch) {
    const int cb = ch % 3, pb = (ch + 2) % 3, nb = (ch + 1) % 3;
    const int cg = ch & 1, ng = 1 - cg;
    const bool lastch = (ch == NCH - 1);

    // ---- P0: w0: reset acc + stage ch+1 ; helpers: C(ch-1)[16..32) + A2(ch)[0..16) ----
    if (w == 0) {
      #pragma unroll
      for (int u = 0; u < 32; ++u) acc[u] = 0.f;
      if (!lastch) {
        const float* src = kallT + (size_t)l * NT + gbase + (ch + 1) * CC;
        float4 v[8];
        #pragma unroll
        for (int q = 0; q < 8; ++q) v[q] = ((const float4*)src)[q];
        #pragma unroll
        for (int q = 0; q < 8; ++q) {
          const int t0 = q * 4;
          kS[nb][(t0+0)*68 + l] = v[q].x; kS[nb][(t0+1)*68 + l] = v[q].y;
          kS[nb][(t0+2)*68 + l] = v[q].z; kS[nb][(t0+3)*68 + l] = v[q].w;
        }
        const float4* gsrc = (const float4*)(Gg + ((size_t)b * NCH + ch + 1) * (CC * CC));
        float4 g[4];
        #pragma unroll
        for (int q = 0; q < 4; ++q) g[q] = gsrc[q * 64 + l];
        #pragma unroll
        for (int q = 0; q < 4; ++q) ((float4*)GS[ng])[q * 64 + l] = g[q];
        if (l < CC) thr2S[ng][l] = thr2_all[gbase + (ch + 1) * CC + l];
        else        invS[nb][l - CC] = inv_all[gbase + (ch + 1) * CC + (l - CC)];
      }
    } else {
      if (ch > 0) C_RUN16(pb, pb, 16);
      A2_RUN16(cb, cb, 0);
    }
    __syncthreads();

    // ---- P1: w0: B[0..16) ; helpers: A2[16..32) ----
    if (w == 0) { B_SLICE(0, cb, cg, lastch); B_SLICE(1, cb, cg, lastch); }
    else        A2_RUN16(cb, cb, 16);
    __syncthreads();

    // ---- P2: w0: B[16..32) ; helpers: C(ch)[0..16) ----
    if (w == 0) { B_SLICE(2, cb, cg, lastch); B_SLICE(3, cb, cg, lastch); }
    else        C_RUN16(cb, cb, 0);
    __syncthreads();
  }

  // ---- epilogue: C(31)[16..32) tail + final read (helpers) ----
  {
    constexpr int fb = (NCH - 1) % 3;   // = 1
    if (w > 0) {
      C_RUN16(fb, fb, 16);
      const float* kr = &kS[fb][(CC - 1) * 68 + jb];
      float p0a=0.f,p0b=0.f,p1a=0.f,p1b=0.f;
      #pragma unroll
      for (int q2 = 0; q2 < 4; ++q2) {
        const float4 kv = ((const float4*)kr)[q2];
        p0a = fmaf(M0[4*q2+0], kv.x, p0a); p0b = fmaf(M0[4*q2+1], kv.y, p0b);
        p0a = fmaf(M0[4*q2+2], kv.z, p0a); p0b = fmaf(M0[4*q2+3], kv.w, p0b);
        p1a = fmaf(M1[4*q2+0], kv.x, p1a); p1b = fmaf(M1[4*q2+1], kv.y, p1b);
        p1a = fmaf(M1[4*q2+2], kv.z, p1a); p1b = fmaf(M1[4*q2+3], kv.w, p1b);
      }
      float d0 = quad_sum(p0a + p0b);
      float d1 = quad_sum(p1a + p1b);
      if (B4 == 0) *(float2*)&readv[b * 64 + r0] = make_float2(d0, d1);
    }
  }
#undef A2_RUN16
#undef C_RUN16
#undef B_SLICE
}

// ---------- Kernel 4: r2T[i][b] = (read @ rpW + rpb)^T ----------
__global__ __launch_bounds__(64) void rproj_kernel(const float* __restrict__ readv,
    const float* __restrict__ rpW, const float* __restrict__ rpb, float* __restrict__ r2T)
{
  const int b = blockIdx.x, i = threadIdx.x;
  const float* rv = readv + b * 64;
  float acc = rpb[i];
  #pragma unroll
  for (int j = 0; j < 64; ++j)
    acc = fmaf(rv[j], rpW[j * 64 + i], acc);
  r2T[i * 64 + b] = acc;
}

// ---------- Kernel 5: out = r2 @ outW + outb (128-thread blocks -> all CUs) ----------
__global__ __launch_bounds__(128, 1) void out_kernel(const float* __restrict__ r2T,
    const float* __restrict__ outW, const float* __restrict__ outb,
    float* __restrict__ out)
{
  const int v = blockIdx.x * 128 + threadIdx.x;
  float acc[64];
  #pragma unroll
  for (int b = 0; b < 64; ++b) acc[b] = 0.f;
  for (int k = 0; k < 64; ++k) {
    const float wv = outW[(size_t)k * NV + v];
    const float* rr = r2T + k * 64;           // uniform row -> s_load
    #pragma unroll
    for (int b = 0; b < 64; ++b)
      acc[b] = fmaf(rr[b], wv, acc[b]);
  }
  const float ob = outb[v];
  #pragma unroll
  for (int b = 0; b < 64; ++b)
    out[(size_t)b * NV + v] = acc[b] + ob;
}

extern "C" void kernel_launch(void* const* d_in, const int* in_sizes, int n_in,
                              void* d_out, int out_size, void* d_ws, size_t ws_size,
                              hipStream_t stream)
{
  const int*   seq   = (const int*)d_in[0];
  const float* embed = (const float*)d_in[1];
  const float* W1    = (const float*)d_in[2];
  const float* b1    = (const float*)d_in[3];
  const float* W2    = (const float*)d_in[4];
  const float* b2    = (const float*)d_in[5];
  const float* gam   = (const float*)d_in[6];
  const float* bet   = (const float*)d_in[7];
  const float* kpW   = (const float*)d_in[8];
  const float* rpW   = (const float*)d_in[9];
  const float* rpb   = (const float*)d_in[10];
  const float* outW  = (const float*)d_in[11];
  const float* outb  = (const float*)d_in[12];
  float* out = (float*)d_out;

  float* ws = (float*)d_ws;
  float* kallT = ws;                                    // 4,194,304 f  [feat][tok]
  float* G     = kallT + (size_t)HDIM * NT;             // 2,097,152 f
  float* thr2  = G     + (size_t)NB * NCH * CC * CC;    //    65,536 f
  float* inv   = thr2  + NT;                            //    65,536 f
  float* readv = inv   + NT;                            //     4,096 f
  float* r2T   = readv + NB * HDIM;                     //     4,096 f
  float* W1T   = r2T   + NB * HDIM;                     //     8,192 f
  float* kpWT  = W1T   + 8192;                          //     4,096 f

  hipLaunchKernelGGL(transpose_w, dim3(48), dim3(256), 0, stream, W1, kpW, W1T, kpWT);
  hipLaunchKernelGGL(tok4, dim3(256), dim3(256), 0, stream,
                     seq, embed, W1T, b1, W2, b2, gam, bet, kpWT, kallT, thr2, inv);
  hipLaunchKernelGGL(gram2, dim3(NB * NCH), dim3(64), 0, stream, kallT, inv, G);
  hipLaunchKernelGGL(scan6, dim3(NB), dim3(192), 0, stream, kallT, thr2, inv, G, readv);
  hipLaunchKernelGGL(rproj_kernel, dim3(NB), dim3(64), 0, stream, readv, rpW, rpb, r2T);
  hipLaunchKernelGGL(out_kernel, dim3(NV / 128), dim3(128), 0, stream, r2T, outW, outb, out);
}

// Round 22
// 460.112 us; speedup vs baseline: 1.1971x; 1.0048x over previous
//
#include <hip/hip_runtime.h>
#include <hip/hip_bf16.h>

#define HDIM 64
#define LSEQ 1024
#define NB 64
#define NV 32000
#define CC 32            // chunk length
#define NCH 32           // chunks per sequence
#define NT (NB * LSEQ)   // total tokens = kallT row stride

// ---------- DPP cross-lane sums (pure VALU) ----------
template<int CTRL>
__device__ __forceinline__ float dpp_red(float x) {
  int y = __builtin_amdgcn_update_dpp(0, __float_as_int(x), CTRL, 0xF, 0xF, true);
  return x + __int_as_float(y);
}
__device__ __forceinline__ float quad_sum(float x) {
  x = dpp_red<0xB1>(x);    // xor 1
  x = dpp_red<0x4E>(x);    // xor 2
  return x;
}
// full-wave sum ending in lane 63 (6 dependent DPP adds, no SALU mixing)
__device__ __forceinline__ float wave_sum63(float x) {
  x = dpp_red<0xB1>(x);    // xor 1
  x = dpp_red<0x4E>(x);    // xor 2
  x = dpp_red<0x141>(x);   // row_half_mirror -> sum of 8
  x = dpp_red<0x140>(x);   // row_mirror      -> sum of 16 (row sums)
  x = dpp_red<0x142>(x);   // + row_bcast15   -> lane63 accumulates rows
  x = dpp_red<0x143>(x);   // + row_bcast31   -> lane 63 holds full sum
  return x;
}

// ---------- Kernel 0: transpose W1 (64x128 -> 128x64) and kpW (64x64) ----------
__global__ __launch_bounds__(256) void transpose_w(const float* __restrict__ W1,
    const float* __restrict__ kpW, float* __restrict__ W1T, float* __restrict__ kpWT)
{
  const int tid = blockIdx.x * 256 + threadIdx.x;
  if (tid < 8192) { const int c = tid >> 6, j = tid & 63; W1T[tid] = W1[j * 128 + c]; }
  else { const int e = tid - 8192; const int i = e >> 6, j = e & 63; kpWT[e] = kpW[j * 64 + i]; }
}

// ---------- Kernel 1: token transform, lane = token ----------
__global__ __launch_bounds__(256, 1) void tok4(
    const int* __restrict__ seq, const float* __restrict__ embed,
    const float* __restrict__ W1T, const float* __restrict__ b1,
    const float* __restrict__ W2, const float* __restrict__ b2,
    const float* __restrict__ gamma, const float* __restrict__ beta,
    const float* __restrict__ kpWT, float* __restrict__ kallT,
    float* __restrict__ thr2_all, float* __restrict__ inv_all)
{
  const int tok = blockIdx.x * 256 + threadIdx.x;
  const int row = seq[tok];
  float h[64], x[64];
  const float4* ep = (const float4*)(embed + (size_t)row * HDIM);
  #pragma unroll
  for (int q = 0; q < 16; ++q) {
    const float4 v = ep[q];
    h[4*q] = v.x; h[4*q+1] = v.y; h[4*q+2] = v.z; h[4*q+3] = v.w;
  }
  #pragma unroll
  for (int j = 0; j < 64; ++j) x[j] = h[j] + b2[j];

  for (int c = 0; c < 128; ++c) {
    const float* w1r = W1T + c * 64;                   // uniform row -> s_load
    float a0 = 0.f, a1 = 0.f, a2 = 0.f, a3 = 0.f;
    #pragma unroll
    for (int j = 0; j < 64; j += 4) {
      a0 = fmaf(h[j],   w1r[j],   a0);
      a1 = fmaf(h[j+1], w1r[j+1], a1);
      a2 = fmaf(h[j+2], w1r[j+2], a2);
      a3 = fmaf(h[j+3], w1r[j+3], a3);
    }
    const float y = fmaxf(b1[c] + ((a0 + a1) + (a2 + a3)), 0.f);
    const float* w2r = W2 + c * 64;
    #pragma unroll
    for (int j = 0; j < 64; ++j) x[j] = fmaf(y, w2r[j], x[j]);
  }

  float s0=0.f,s1=0.f,s2=0.f,s3=0.f,q0=0.f,q1=0.f,q2=0.f,q3=0.f;
  #pragma unroll
  for (int j = 0; j < 64; j += 4) {
    s0 += x[j]; s1 += x[j+1]; s2 += x[j+2]; s3 += x[j+3];
    q0 = fmaf(x[j],   x[j],   q0); q1 = fmaf(x[j+1], x[j+1], q1);
    q2 = fmaf(x[j+2], x[j+2], q2); q3 = fmaf(x[j+3], x[j+3], q3);
  }
  const float mu  = ((s0+s1)+(s2+s3)) * (1.f/64.f);
  const float var = ((q0+q1)+(q2+q3)) * (1.f/64.f) - mu * mu;
  const float rs  = rsqrtf(var + 1e-5f);
  #pragma unroll
  for (int j = 0; j < 64; ++j) h[j] = (x[j] - mu) * rs * gamma[j] + beta[j];

  float nk2 = 0.f;
  for (int i = 0; i < 64; ++i) {
    const float* kr = kpWT + i * 64;                   // uniform row -> s_load
    float c0=0.f,c1=0.f,c2=0.f,c3=0.f;
    #pragma unroll
    for (int j = 0; j < 64; j += 4) {
      c0 = fmaf(h[j],   kr[j],   c0);
      c1 = fmaf(h[j+1], kr[j+1], c1);
      c2 = fmaf(h[j+2], kr[j+2], c2);
      c3 = fmaf(h[j+3], kr[j+3], c3);
    }
    const float ki = (c0 + c1) + (c2 + c3);
    nk2 = fmaf(ki, ki, nk2);
    kallT[(size_t)i * NT + tok] = ki;
  }
  thr2_all[tok] = 0.16f * nk2;
  inv_all[tok]  = 1.f / fmaxf(sqrtf(nk2), 1e-12f);
}

// ---------- Kernel 2: per-chunk normalized Gram ----------
__global__ __launch_bounds__(64) void gram2(const float* __restrict__ kallT,
    const float* __restrict__ inv_all, float* __restrict__ Gg)
{
  const int bi = blockIdx.x;
  const int b = bi >> 5, ch = bi & 31;
  const int l = threadIdx.x;
  const int t0 = (l & 7) * 4, s0 = (l >> 3) * 4;
  const size_t gb = (size_t)b * LSEQ + ch * CC;
  float g00=0,g01=0,g02=0,g03=0, g10=0,g11=0,g12=0,g13=0;
  float g20=0,g21=0,g22=0,g23=0, g30=0,g31=0,g32=0,g33=0;
  for (int j = 0; j < 64; ++j) {
    const float* rowp = kallT + (size_t)j * NT + gb;
    const float4 a = *(const float4*)(rowp + t0);
    const float4 c = *(const float4*)(rowp + s0);
    g00=fmaf(a.x,c.x,g00); g01=fmaf(a.x,c.y,g01); g02=fmaf(a.x,c.z,g02); g03=fmaf(a.x,c.w,g03);
    g10=fmaf(a.y,c.x,g10); g11=fmaf(a.y,c.y,g11); g12=fmaf(a.y,c.z,g12); g13=fmaf(a.y,c.w,g13);
    g20=fmaf(a.z,c.x,g20); g21=fmaf(a.z,c.y,g21); g22=fmaf(a.z,c.z,g22); g23=fmaf(a.z,c.w,g23);
    g30=fmaf(a.w,c.x,g30); g31=fmaf(a.w,c.y,g31); g32=fmaf(a.w,c.z,g32); g33=fmaf(a.w,c.w,g33);
  }
  const float4 it = *(const float4*)(inv_all + gb + t0);
  const float4 is = *(const float4*)(inv_all + gb + s0);
  float* Go = Gg + (size_t)bi * (CC * CC);
  float4 o;
  o.x=g00*it.x*is.x; o.y=g01*it.x*is.y; o.z=g02*it.x*is.z; o.w=g03*it.x*is.w;
  *(float4*)(Go + (t0+0)*CC + s0) = o;
  o.x=g10*it.y*is.x; o.y=g11*it.y*is.y; o.z=g12*it.y*is.z; o.w=g13*it.y*is.w;
  *(float4*)(Go + (t0+1)*CC + s0) = o;
  o.x=g20*it.z*is.x; o.y=g21*it.z*is.y; o.z=g22*it.z*is.z; o.w=g23*it.z*is.w;
  *(float4*)(Go + (t0+2)*CC + s0) = o;
  o.x=g30*it.w*is.x; o.y=g31*it.w*is.y; o.z=g32*it.w*is.z; o.w=g33*it.w*is.w;
  *(float4*)(Go + (t0+3)*CC + s0) = o;
}

// ---------- Kernel 3: chunked gated delta scan + fused read-projection ----------
// Measured-best r7 structure (scan6 209 us), plus: rproj fused into the
// epilogue (helpers deposit read vector into rS; w0 lanes 0..63 compute
// r2T[i][b] with the exact rproj FMA order). One fewer kernel launch.
__global__ __launch_bounds__(192, 1) void scan6(
    const float* __restrict__ kallT, const float* __restrict__ thr2_all,
    const float* __restrict__ inv_all, const float* __restrict__ Gg,
    const float* __restrict__ rpW, const float* __restrict__ rpb,
    float* __restrict__ r2T)
{
  __shared__ float kS[3][CC * 68];
  __shared__ float GS[2][CC * CC];
  __shared__ float rS[CC * 64];
  __shared__ float cstS[CC * 64];
  __shared__ float thr2S[2][CC];
  __shared__ float invS[3][CC];

  const int b = blockIdx.x, tid = threadIdx.x;
  const int w = tid >> 6, l = tid & 63;
  const int A = l >> 2, B4 = l & 3;
  const int r0 = 32 * (w - 1) + 2 * A;   // helper rows (w>0)
  const int jb = 16 * B4;
  const size_t gbase = (size_t)b * LSEQ;

  float M0[16], M1[16], acc[32];
  #pragma unroll
  for (int q = 0; q < 16; ++q) { M0[q] = 0.f; M1[q] = 0.f; }

// A2 over 16 tokens with k/inv double-buffered register prefetch.
#define A2_RUN16(KB, IB, T0) do {                                              \
    const float* kr0_ = &kS[KB][(T0) * 68 + jb];                               \
    float4 kA0 = ((const float4*)kr0_)[0], kA1 = ((const float4*)kr0_)[1],     \
           kA2 = ((const float4*)kr0_)[2], kA3 = ((const float4*)kr0_)[3];     \
    float  ivA = invS[IB][(T0)];                                               \
    float4 kB0, kB1, kB2, kB3; float ivB = 0.f;                                \
    _Pragma("unroll")                                                          \
    for (int i = 0; i < 16; ++i) {                                             \
      const int t = (T0) + i;                                                  \
      if (i < 15) {                                                            \
        const float* knx_ = &kS[KB][(t + 1) * 68 + jb];                        \
        if ((i & 1) == 0) {                                                    \
          kB0 = ((const float4*)knx_)[0]; kB1 = ((const float4*)knx_)[1];      \
          kB2 = ((const float4*)knx_)[2]; kB3 = ((const float4*)knx_)[3];      \
          ivB = invS[IB][t + 1];                                               \
        } else {                                                               \
          kA0 = ((const float4*)knx_)[0]; kA1 = ((const float4*)knx_)[1];      \
          kA2 = ((const float4*)knx_)[2]; kA3 = ((const float4*)knx_)[3];      \
          ivA = invS[IB][t + 1];                                               \
        }                                                                      \
      }                                                                        \
      float4 kq[4]; float iv;                                                  \
      if ((i & 1) == 0) { kq[0]=kA0; kq[1]=kA1; kq[2]=kA2; kq[3]=kA3; iv=ivA; }\
      else              { kq[0]=kB0; kq[1]=kB1; kq[2]=kB2; kq[3]=kB3; iv=ivB; }\
      float p0a=0.f,p0b=0.f,p1a=0.f,p1b=0.f;                                   \
      _Pragma("unroll")                                                        \
      for (int q2 = 0; q2 < 4; ++q2) {                                         \
        const float4 kv = kq[q2];                                              \
        p0a = fmaf(M0[4*q2+0], kv.x, p0a); p0b = fmaf(M0[4*q2+1], kv.y, p0b);  \
        p0a = fmaf(M0[4*q2+2], kv.z, p0a); p0b = fmaf(M0[4*q2+3], kv.w, p0b);  \
        p1a = fmaf(M1[4*q2+0], kv.x, p1a); p1b = fmaf(M1[4*q2+1], kv.y, p1b);  \
        p1a = fmaf(M1[4*q2+2], kv.z, p1a); p1b = fmaf(M1[4*q2+3], kv.w, p1b);  \
      }                                                                        \
      float p0 = quad_sum(p0a + p0b);                                          \
      float p1 = quad_sum(p1a + p1b);                                          \
      if (B4 == 0) *(float2*)&rS[t * 64 + r0] = make_float2(p0 * iv, p1 * iv); \
    }                                                                          \
  } while (0)

// C over 16 tokens with k/cst/inv double-buffered register prefetch.
#define C_RUN16(KB, IB, S0) do {                                               \
    const float* kr0_ = &kS[KB][(S0) * 68 + jb];                               \
    float4 kA0 = ((const float4*)kr0_)[0], kA1 = ((const float4*)kr0_)[1],     \
           kA2 = ((const float4*)kr0_)[2], kA3 = ((const float4*)kr0_)[3];     \
    float2 cA  = *(const float2*)&cstS[(S0) * 64 + r0];                        \
    float  ivA = invS[IB][(S0)];                                               \
    float4 kB0, kB1, kB2, kB3; float2 cB = make_float2(0.f, 0.f); float ivB = 0.f; \
    _Pragma("unroll")                                                          \
    for (int i = 0; i < 16; ++i) {                                             \
      const int s = (S0) + i;                                                  \
      if (i < 15) {                                                            \
        const float* knx_ = &kS[KB][(s + 1) * 68 + jb];                        \
        if ((i & 1) == 0) {                                                    \
          kB0 = ((const float4*)knx_)[0]; kB1 = ((const float4*)knx_)[1];      \
          kB2 = ((const float4*)knx_)[2]; kB3 = ((const float4*)knx_)[3];      \
          cB  = *(const float2*)&cstS[(s + 1) * 64 + r0];                      \
          ivB = invS[IB][s + 1];                                               \
        } else {                                                               \
          kA0 = ((const float4*)knx_)[0]; kA1 = ((const float4*)knx_)[1];      \
          kA2 = ((const float4*)knx_)[2]; kA3 = ((const float4*)knx_)[3];      \
          cA  = *(const float2*)&cstS[(s + 1) * 64 + r0];                      \
          ivA = invS[IB][s + 1];                                               \
        }                                                                      \
      }                                                                        \
      float4 kq[4]; float2 cc2; float iv;                                      \
      if ((i & 1) == 0) { kq[0]=kA0; kq[1]=kA1; kq[2]=kA2; kq[3]=kA3; cc2=cA; iv=ivA; } \
      else              { kq[0]=kB0; kq[1]=kB1; kq[2]=kB2; kq[3]=kB3; cc2=cB; iv=ivB; } \
      const float c0 = cc2.x * iv, c1 = cc2.y * iv;                            \
      _Pragma("unroll")                                                        \
      for (int q2 = 0; q2 < 4; ++q2) {                                         \
        const float4 kv = kq[q2];                                              \
        M0[4*q2+0] = fmaf(c0, kv.x, M0[4*q2+0]); M0[4*q2+1] = fmaf(c0, kv.y, M0[4*q2+1]); \
        M0[4*q2+2] = fmaf(c0, kv.z, M0[4*q2+2]); M0[4*q2+3] = fmaf(c0, kv.w, M0[4*q2+3]); \
        M1[4*q2+0] = fmaf(c1, kv.x, M1[4*q2+0]); M1[4*q2+1] = fmaf(c1, kv.y, M1[4*q2+1]); \
        M1[4*q2+2] = fmaf(c1, kv.z, M1[4*q2+2]); M1[4*q2+3] = fmaf(c1, kv.w, M1[4*q2+3]); \
      }                                                                        \
    }                                                                          \
  } while (0)

// B: serial gate core, tokens [8Q, 8Q+8), software-pipelined (measured r5-r7)
#define B_SLICE(Q, CBUF, CGI, LASTCH) do {                                     \
    const int t0_ = 8 * (Q);                                                   \
    float kr_[8], rr_[8];                                                      \
    _Pragma("unroll")                                                          \
    for (int i = 0; i < 8; ++i) {                                              \
      kr_[i] = kS[CBUF][(t0_ + i) * 68 + l];                                   \
      rr_[i] = rS[(t0_ + i) * 64 + l];                                         \
    }                                                                          \
    const float4 tha = ((const float4*)&thr2S[CGI][t0_])[0];                   \
    const float4 thb = ((const float4*)&thr2S[CGI][t0_])[1];                   \
    const float th8[8] = {tha.x,tha.y,tha.z,tha.w, thb.x,thb.y,thb.z,thb.w};   \
    float g2_[2][32];                                                          \
    _Pragma("unroll")                                                          \
    for (int q = (t0_ + 1) >> 2; q < 8; ++q) {                                 \
      const float4 v = ((const float4*)&GS[CGI][t0_ * 32])[q];                 \
      g2_[0][4*q+0] = v.x; g2_[0][4*q+1] = v.y;                                \
      g2_[0][4*q+2] = v.z; g2_[0][4*q+3] = v.w;                                \
    }                                                                          \
    float err_ = acc[t0_] + kr_[0] - rr_[0];                                   \
    float red_ = wave_sum63(err_ * err_);                                      \
    _Pragma("unroll")                                                          \
    for (int i = 0; i < 8; ++i) {                                              \
      const int t = t0_ + i;                                                   \
      if (i < 7) {                                                             \
        _Pragma("unroll")                                                      \
        for (int q = (t + 2) >> 2; q < 8; ++q) {                               \
          const float4 v = ((const float4*)&GS[CGI][(t + 1) * 32])[q];         \
          g2_[(i+1)&1][4*q+0] = v.x; g2_[(i+1)&1][4*q+1] = v.y;                \
          g2_[(i+1)&1][4*q+2] = v.z; g2_[(i+1)&1][4*q+3] = v.w;                \
        }                                                                      \
      }                                                                        \
      const float ne2_ = __int_as_float(                                       \
          __builtin_amdgcn_readlane(__float_as_int(red_), 63));                \
      bool gate_ = (ne2_ >= th8[i]);                                           \
      if ((LASTCH) && t == CC - 1) gate_ = false;                              \
      const float c = gate_ ? err_ : 0.f;                                      \
      cstS[t * 64 + l] = c;                                                    \
      if (i < 7) {                                                             \
        acc[t + 1] = fmaf(-g2_[i & 1][t + 1], c, acc[t + 1]);                  \
        err_ = acc[t + 1] + kr_[i + 1] - rr_[i + 1];                           \
        red_ = wave_sum63(err_ * err_);                                        \
      }                                                                        \
      _Pragma("unroll")                                                        \
      for (int u = (i < 7) ? (t + 2) : (t + 1); u < CC; ++u)                   \
        acc[u] = fmaf(-g2_[i & 1][u], c, acc[u]);                              \
    }                                                                          \
  } while (0)

  // ---- prologue: stage chunk 0 ----
  if (w < 2) {
    const float* src = kallT + (size_t)l * NT + gbase + w * 16;
    float4 v[4];
    #pragma unroll
    for (int q = 0; q < 4; ++q) v[q] = ((const float4*)src)[q];
    #pragma unroll
    for (int q = 0; q < 4; ++q) {
      const int t0 = w * 16 + q * 4;
      kS[0][(t0+0)*68 + l] = v[q].x; kS[0][(t0+1)*68 + l] = v[q].y;
      kS[0][(t0+2)*68 + l] = v[q].z; kS[0][(t0+3)*68 + l] = v[q].w;
    }
  } else {
    const float4* gsrc = (const float4*)(Gg + (size_t)b * NCH * (CC * CC));
    float4 g[4];
    #pragma unroll
    for (int q = 0; q < 4; ++q) g[q] = gsrc[q * 64 + l];
    #pragma unroll
    for (int q = 0; q < 4; ++q) ((float4*)GS[0])[q * 64 + l] = g[q];
    if (l < CC) thr2S[0][l] = thr2_all[gbase + l];
    else        invS[0][l - CC] = inv_all[gbase + (l - CC)];
  }
  __syncthreads();

  for (int ch = 0; ch < NCH; ++ch) {
    const int cb = ch % 3, pb = (ch + 2) % 3, nb = (ch + 1) % 3;
    const int cg = ch & 1, ng = 1 - cg;
    const bool lastch = (ch == NCH - 1);

    // ---- P0: w0: reset acc + stage ch+1 ; helpers: C(ch-1)[16..32) + A2(ch)[0..16) ----
    if (w == 0) {
      #pragma unroll
      for (int u = 0; u < 32; ++u) acc[u] = 0.f;
      if (!lastch) {
        const float* src = kallT + (size_t)l * NT + gbase + (ch + 1) * CC;
        float4 v[8];
        #pragma unroll
        for (int q = 0; q < 8; ++q) v[q] = ((const float4*)src)[q];
        #pragma unroll
        for (int q = 0; q < 8; ++q) {
          const int t0 = q * 4;
          kS[nb][(t0+0)*68 + l] = v[q].x; kS[nb][(t0+1)*68 + l] = v[q].y;
          kS[nb][(t0+2)*68 + l] = v[q].z; kS[nb][(t0+3)*68 + l] = v[q].w;
        }
        const float4* gsrc = (const float4*)(Gg + ((size_t)b * NCH + ch + 1) * (CC * CC));
        float4 g[4];
        #pragma unroll
        for (int q = 0; q < 4; ++q) g[q] = gsrc[q * 64 + l];
        #pragma unroll
        for (int q = 0; q < 4; ++q) ((float4*)GS[ng])[q * 64 + l] = g[q];
        if (l < CC) thr2S[ng][l] = thr2_all[gbase + (ch + 1) * CC + l];
        else        invS[nb][l - CC] = inv_all[gbase + (ch + 1) * CC + (l - CC)];
      }
    } else {
      if (ch > 0) C_RUN16(pb, pb, 16);
      A2_RUN16(cb, cb, 0);
    }
    __syncthreads();

    // ---- P1: w0: B[0..16) ; helpers: A2[16..32) ----
    if (w == 0) { B_SLICE(0, cb, cg, lastch); B_SLICE(1, cb, cg, lastch); }
    else        A2_RUN16(cb, cb, 16);
    __syncthreads();

    // ---- P2: w0: B[16..32) ; helpers: C(ch)[0..16) ----
    if (w == 0) { B_SLICE(2, cb, cg, lastch); B_SLICE(3, cb, cg, lastch); }
    else        C_RUN16(cb, cb, 0);
    __syncthreads();
  }

  // ---- epilogue: C(31)[16..32) tail + final read -> rS ; fused rproj ----
  {
    constexpr int fb = (NCH - 1) % 3;   // = 1
    if (w > 0) {
      C_RUN16(fb, fb, 16);
      const float* kr = &kS[fb][(CC - 1) * 68 + jb];
      float p0a=0.f,p0b=0.f,p1a=0.f,p1b=0.f;
      #pragma unroll
      for (int q2 = 0; q2 < 4; ++q2) {
        const float4 kv = ((const float4*)kr)[q2];
        p0a = fmaf(M0[4*q2+0], kv.x, p0a); p0b = fmaf(M0[4*q2+1], kv.y, p0b);
        p0a = fmaf(M0[4*q2+2], kv.z, p0a); p0b = fmaf(M0[4*q2+3], kv.w, p0b);
        p1a = fmaf(M1[4*q2+0], kv.x, p1a); p1b = fmaf(M1[4*q2+1], kv.y, p1b);
        p1a = fmaf(M1[4*q2+2], kv.z, p1a); p1b = fmaf(M1[4*q2+3], kv.w, p1b);
      }
      float d0 = quad_sum(p0a + p0b);
      float d1 = quad_sum(p1a + p1b);
      if (B4 == 0) { rS[r0] = d0; rS[r0 + 1] = d1; }
    }
    __syncthreads();
    // fused rproj: r2T[i][b] = rpb[i] + sum_j rS[j] * rpW[j*64+i]
    // (identical FMA order to the former rproj_kernel -> bit-exact)
    if (tid < 64) {
      const int i = tid;
      float acc2 = rpb[i];
      #pragma unroll
      for (int j = 0; j < 64; ++j)
        acc2 = fmaf(rS[j], rpW[j * 64 + i], acc2);
      r2T[i * 64 + b] = acc2;
    }
  }
#undef A2_RUN16
#undef C_RUN16
#undef B_SLICE
}

// ---------- Kernel 5: out = r2 @ outW + outb (128-thread blocks -> all CUs) ----------
__global__ __launch_bounds__(128, 1) void out_kernel(const float* __restrict__ r2T,
    const float* __restrict__ outW, const float* __restrict__ outb,
    float* __restrict__ out)
{
  const int v = blockIdx.x * 128 + threadIdx.x;
  float acc[64];
  #pragma unroll
  for (int b = 0; b < 64; ++b) acc[b] = 0.f;
  for (int k = 0; k < 64; ++k) {
    const float wv = outW[(size_t)k * NV + v];
    const float* rr = r2T + k * 64;           // uniform row -> s_load
    #pragma unroll
    for (int b = 0; b < 64; ++b)
      acc[b] = fmaf(rr[b], wv, acc[b]);
  }
  const float ob = outb[v];
  #pragma unroll
  for (int b = 0; b < 64; ++b)
    out[(size_t)b * NV + v] = acc[b] + ob;
}

extern "C" void kernel_launch(void* const* d_in, const int* in_sizes, int n_in,
                              void* d_out, int out_size, void* d_ws, size_t ws_size,
                              hipStream_t stream)
{
  const int*   seq   = (const int*)d_in[0];
  const float* embed = (const float*)d_in[1];
  const float* W1    = (const float*)d_in[2];
  const float* b1    = (const float*)d_in[3];
  const float* W2    = (const float*)d_in[4];
  const float* b2    = (const float*)d_in[5];
  const float* gam   = (const float*)d_in[6];
  const float* bet   = (const float*)d_in[7];
  const float* kpW   = (const float*)d_in[8];
  const float* rpW   = (const float*)d_in[9];
  const float* rpb   = (const float*)d_in[10];
  const float* outW  = (const float*)d_in[11];
  const float* outb  = (const float*)d_in[12];
  float* out = (float*)d_out;

  float* ws = (float*)d_ws;
  float* kallT = ws;                                    // 4,194,304 f  [feat][tok]
  float* G     = kallT + (size_t)HDIM * NT;             // 2,097,152 f
  float* thr2  = G     + (size_t)NB * NCH * CC * CC;    //    65,536 f
  float* inv   = thr2  + NT;                            //    65,536 f
  float* readv = inv   + NT;                            //     4,096 f (unused)
  float* r2T   = readv + NB * HDIM;                     //     4,096 f
  float* W1T   = r2T   + NB * HDIM;                     //     8,192 f
  float* kpWT  = W1T   + 8192;                          //     4,096 f

  hipLaunchKernelGGL(transpose_w, dim3(48), dim3(256), 0, stream, W1, kpW, W1T, kpWT);
  hipLaunchKernelGGL(tok4, dim3(256), dim3(256), 0, stream,
                     seq, embed, W1T, b1, W2, b2, gam, bet, kpWT, kallT, thr2, inv);
  hipLaunchKernelGGL(gram2, dim3(NB * NCH), dim3(64), 0, stream, kallT, inv, G);
  hipLaunchKernelGGL(scan6, dim3(NB), dim3(192), 0, stream, kallT, thr2, inv, G,
                     rpW, rpb, r2T);
  hipLaunchKernelGGL(out_kernel, dim3(NV / 128), dim3(128), 0, stream, r2T, outW, outb, out);
}